// Round 1
// baseline (1024.214 us; speedup 1.0000x reference)
//
#include <hip/hip_runtime.h>
#include <hip/hip_bf16.h>

#define NN 50000
#define NE 400000
#define DD 100

// workspace layout (float offsets, all 16-float aligned where it matters)
#define OFF_P   0
#define OFF_Q   112
#define OFF_C   224
#define OFF_S   240
#define OFF_T   (OFF_S + NN)        // 50240
#define OFF_DEN (OFF_T + NN)        // 100240
#define OFF_Z   (OFF_DEN + NN + 16) // 150256

// K0: fold W_rel/b_rel/W_attn into p[100], q[100], c
__global__ void k_prep(const float* __restrict__ W_rel, const float* __restrict__ b_rel,
                       const float* __restrict__ W_attn, float* __restrict__ ws) {
    int t = threadIdx.x;
    if (t < DD) {
        float accp = 0.f, accq = 0.f;
        for (int j = 0; j < DD; ++j) {
            float v = W_attn[DD + j];
            accp = fmaf(W_rel[t * DD + j], v, accp);
            accq = fmaf(W_rel[(DD + t) * DD + j], v, accq);
        }
        ws[OFF_P + t] = accp;
        ws[OFF_Q + t] = accq;
    } else if (t == DD) {
        float accc = 0.f;
        for (int j = 0; j < DD; ++j) accc = fmaf(b_rel[j], W_attn[DD + j], accc);
        ws[OFF_C] = accc;
    }
}

// K1: z = x @ W_fc  (thread = row, x tile staged in LDS, W_fc via uniform scalar loads)
//     also s[i] = z_i . u   (u = W_attn[:100]),  t[i] = z_i . q
__launch_bounds__(128)
__global__ void k_fc(const float* __restrict__ x, const float* __restrict__ W_fc,
                     const float* __restrict__ W_attn, float* __restrict__ ws) {
    __shared__ float xs[128 * 101];   // pad 101 -> conflict-free per-lane row reads
    int tid = threadIdx.x;
    int row0 = blockIdx.x * 128;
    int nrows = NN - row0; if (nrows > 128) nrows = 128;
    int n4 = nrows * 25;
    const float4* x4 = reinterpret_cast<const float4*>(x + (size_t)row0 * DD);
    for (int i = tid; i < 128 * 25; i += 128) {
        float4 v = (i < n4) ? x4[i] : make_float4(0.f, 0.f, 0.f, 0.f);
        int r = i / 25, c4 = i - r * 25;
        int base = r * 101 + c4 * 4;
        xs[base] = v.x; xs[base + 1] = v.y; xs[base + 2] = v.z; xs[base + 3] = v.w;
    }
    __syncthreads();

    int row = row0 + tid;
    float z_s = 0.f, z_t = 0.f;
    float* zrow = ws + OFF_Z + (size_t)row * DD;
    for (int half = 0; half < 2; ++half) {
        float acc[50];
        #pragma unroll
        for (int c = 0; c < 50; ++c) acc[c] = 0.f;
        const float* Wb = W_fc + half * 50;           // uniform address -> s_load
        for (int k = 0; k < DD; ++k) {
            float xv = xs[tid * 101 + k];
            #pragma unroll
            for (int c = 0; c < 50; ++c) acc[c] = fmaf(xv, Wb[k * DD + c], acc[c]);
        }
        if (row < NN) {
            const float* u = W_attn + half * 50;      // uniform
            const float* q = ws + OFF_Q + half * 50;  // uniform
            #pragma unroll
            for (int c = 0; c < 50; ++c) {
                z_s = fmaf(acc[c], u[c], z_s);
                z_t = fmaf(acc[c], q[c], z_t);
            }
            #pragma unroll
            for (int c = 0; c < 50; c += 2) {
                float2 st; st.x = acc[c]; st.y = acc[c + 1];
                *reinterpret_cast<float2*>(zrow + half * 50 + c) = st;
            }
        }
    }
    if (row < NN) { ws[OFF_S + row] = z_s; ws[OFF_T + row] = z_t; }
}

// K2: one pass over edges. 4 lanes per edge.
//   a = p.edge_h + s[src] + t[dst] + c ; ex = exp(leaky_relu(a))
//   denom[dst] += ex ; h[dst] += ex * z[src]   (unnormalized)
__launch_bounds__(256)
__global__ void k_edge(const float* __restrict__ edge_h, const int* __restrict__ src,
                       const int* __restrict__ dst, float* __restrict__ ws,
                       float* __restrict__ h) {
    const float* p = ws + OFF_P;
    const float* z = ws + OFF_Z;
    float* denom = ws + OFF_DEN;
    const float cterm = ws[OFF_C];
    const int part = threadIdx.x & 3;

    float4 pf[6];
    #pragma unroll
    for (int j = 0; j < 6; ++j)
        pf[j] = *reinterpret_cast<const float4*>(p + part * 4 + j * 16);
    const float ptail = p[96 + part];

    const int groups_per_iter = (gridDim.x * blockDim.x) >> 2;
    const int g0 = (blockIdx.x * blockDim.x + threadIdx.x) >> 2;

    for (int e = g0; e < NE; e += groups_per_iter) {
        const float* eh = edge_h + (size_t)e * DD;
        float pd = 0.f;
        #pragma unroll
        for (int j = 0; j < 6; ++j) {
            float4 v = *reinterpret_cast<const float4*>(eh + part * 4 + j * 16);
            pd = fmaf(v.x, pf[j].x, pd);
            pd = fmaf(v.y, pf[j].y, pd);
            pd = fmaf(v.z, pf[j].z, pd);
            pd = fmaf(v.w, pf[j].w, pd);
        }
        pd = fmaf(eh[96 + part], ptail, pd);
        pd += __shfl_xor(pd, 1);
        pd += __shfl_xor(pd, 2);

        int sn = src[e], dn = dst[e];
        float a = pd + ws[OFF_S + sn] + ws[OFF_T + dn] + cterm;
        float ev = a > 0.f ? a : 0.01f * a;
        float ex = __expf(ev);
        if (part == 0) atomicAdd(&denom[dn], ex);

        const float* zr = z + (size_t)sn * DD;
        float* hr = h + (size_t)dn * DD;
        #pragma unroll
        for (int j = 0; j < 6; ++j) {
            int base = part * 4 + j * 16;
            float4 v = *reinterpret_cast<const float4*>(zr + base);
            atomicAdd(&hr[base + 0], ex * v.x);
            atomicAdd(&hr[base + 1], ex * v.y);
            atomicAdd(&hr[base + 2], ex * v.z);
            atomicAdd(&hr[base + 3], ex * v.w);
        }
        atomicAdd(&hr[96 + part], ex * zr[96 + part]);
    }
}

// K3: h /= denom (guard zero-in-degree -> 0)
__global__ void k_scale(float* __restrict__ h, const float* __restrict__ ws) {
    int i4 = blockIdx.x * blockDim.x + threadIdx.x;  // float4 index
    if (i4 >= NN * 25) return;
    int n = i4 / 25;
    float d = ws[OFF_DEN + n];
    float inv = (d > 0.f) ? 1.0f / d : 0.f;
    float4 v = reinterpret_cast<float4*>(h)[i4];
    v.x *= inv; v.y *= inv; v.z *= inv; v.w *= inv;
    reinterpret_cast<float4*>(h)[i4] = v;
}

extern "C" void kernel_launch(void* const* d_in, const int* in_sizes, int n_in,
                              void* d_out, int out_size, void* d_ws, size_t ws_size,
                              hipStream_t stream) {
    const float* x      = (const float*)d_in[0];
    const float* edge_h = (const float*)d_in[1];
    const int*   src    = (const int*)d_in[2];
    const int*   dst    = (const int*)d_in[3];
    const float* W_fc   = (const float*)d_in[4];
    const float* W_rel  = (const float*)d_in[5];
    const float* b_rel  = (const float*)d_in[6];
    const float* W_attn = (const float*)d_in[7];
    float* h  = (float*)d_out;
    float* ws = (float*)d_ws;

    hipMemsetAsync(h, 0, (size_t)NN * DD * sizeof(float), stream);
    hipMemsetAsync(ws + OFF_DEN, 0, (size_t)NN * sizeof(float), stream);

    k_prep<<<1, 128, 0, stream>>>(W_rel, b_rel, W_attn, ws);
    k_fc<<<(NN + 127) / 128, 128, 0, stream>>>(x, W_fc, W_attn, ws);
    k_edge<<<2048, 256, 0, stream>>>(edge_h, src, dst, ws, h);
    k_scale<<<(NN * 25 + 255) / 256, 256, 0, stream>>>(h, ws);
}

// Round 2
// 277.701 us; speedup vs baseline: 3.6882x; 3.6882x over previous
//
#include <hip/hip_runtime.h>
#include <hip/hip_bf16.h>

#define NN 50000
#define NE 400000
#define DD 100

// workspace layout (float offsets)
#define OFF_P    0
#define OFF_Q    112
#define OFF_C    224
#define OFF_S    240
#define OFF_T    (OFF_S + NN)          // 50240
#define OFF_CNT  (OFF_T + NN)          // 100240  (ints; becomes run-cursor after scan)
#define OFF_OFFS (OFF_CNT + NN)        // 150240  (ints, NN+1)
#define OFF_PAY  (OFF_OFFS + NN + 16)  // 200256  (float2 per edge: src bits, ex)
#define OFF_Z    (OFF_PAY + 2 * NE)    // 1000256

#define SCAN_T 1024
#define SCAN_CH ((NN + SCAN_T - 1) / SCAN_T)   // 49

// K0: fold W_rel/b_rel/W_attn into p[100], q[100], c
__global__ void k_prep(const float* __restrict__ W_rel, const float* __restrict__ b_rel,
                       const float* __restrict__ W_attn, float* __restrict__ ws) {
    int t = threadIdx.x;
    if (t < DD) {
        float accp = 0.f, accq = 0.f;
        for (int j = 0; j < DD; ++j) {
            float v = W_attn[DD + j];
            accp = fmaf(W_rel[t * DD + j], v, accp);
            accq = fmaf(W_rel[(DD + t) * DD + j], v, accq);
        }
        ws[OFF_P + t] = accp;
        ws[OFF_Q + t] = accq;
    } else if (t == DD) {
        float accc = 0.f;
        for (int j = 0; j < DD; ++j) accc = fmaf(b_rel[j], W_attn[DD + j], accc);
        ws[OFF_C] = accc;
    }
}

// K1: z = x @ W_fc (thread = row, x tile in LDS), plus s[i]=z_i.u, t[i]=z_i.q
__launch_bounds__(128)
__global__ void k_fc(const float* __restrict__ x, const float* __restrict__ W_fc,
                     const float* __restrict__ W_attn, float* __restrict__ ws) {
    __shared__ float xs[128 * 101];
    int tid = threadIdx.x;
    int row0 = blockIdx.x * 128;
    int nrows = NN - row0; if (nrows > 128) nrows = 128;
    int n4 = nrows * 25;
    const float4* x4 = reinterpret_cast<const float4*>(x + (size_t)row0 * DD);
    for (int i = tid; i < 128 * 25; i += 128) {
        float4 v = (i < n4) ? x4[i] : make_float4(0.f, 0.f, 0.f, 0.f);
        int r = i / 25, c4 = i - r * 25;
        int base = r * 101 + c4 * 4;
        xs[base] = v.x; xs[base + 1] = v.y; xs[base + 2] = v.z; xs[base + 3] = v.w;
    }
    __syncthreads();

    int row = row0 + tid;
    float z_s = 0.f, z_t = 0.f;
    float* zrow = ws + OFF_Z + (size_t)row * DD;
    for (int half = 0; half < 2; ++half) {
        float acc[50];
        #pragma unroll
        for (int c = 0; c < 50; ++c) acc[c] = 0.f;
        const float* Wb = W_fc + half * 50;           // uniform -> s_load
        for (int k = 0; k < DD; ++k) {
            float xv = xs[tid * 101 + k];
            #pragma unroll
            for (int c = 0; c < 50; ++c) acc[c] = fmaf(xv, Wb[k * DD + c], acc[c]);
        }
        if (row < NN) {
            const float* u = W_attn + half * 50;
            const float* q = ws + OFF_Q + half * 50;
            #pragma unroll
            for (int c = 0; c < 50; ++c) {
                z_s = fmaf(acc[c], u[c], z_s);
                z_t = fmaf(acc[c], q[c], z_t);
            }
            #pragma unroll
            for (int c = 0; c < 50; c += 2) {
                float2 st; st.x = acc[c]; st.y = acc[c + 1];
                *reinterpret_cast<float2*>(zrow + half * 50 + c) = st;
            }
        }
    }
    if (row < NN) { ws[OFF_S + row] = z_s; ws[OFF_T + row] = z_t; }
}

// K2a: histogram of dst
__global__ void k_hist(const int* __restrict__ dst, float* __restrict__ ws) {
    int e = blockIdx.x * blockDim.x + threadIdx.x;
    if (e < NE) {
        int* cnt = (int*)(ws + OFF_CNT);
        atomicAdd(&cnt[dst[e]], 1);
    }
}

// K2b: single-block exclusive scan of cnt -> offs; cnt[i] := offs[i] (scatter cursor)
__launch_bounds__(SCAN_T)
__global__ void k_scan(float* __restrict__ ws) {
    __shared__ int sums[SCAN_T];
    int* cnt  = (int*)(ws + OFF_CNT);
    int* offs = (int*)(ws + OFF_OFFS);
    int t = threadIdx.x;
    int beg = t * SCAN_CH;
    int end = beg + SCAN_CH; if (end > NN) end = NN;
    int s = 0;
    for (int i = beg; i < end; ++i) s += cnt[i];
    sums[t] = s;
    for (int off = 1; off < SCAN_T; off <<= 1) {
        __syncthreads();
        int v = (t >= off) ? sums[t - off] : 0;
        __syncthreads();
        sums[t] += v;
    }
    __syncthreads();
    int run = (t > 0) ? sums[t - 1] : 0;
    for (int i = beg; i < end; ++i) {
        int cv = cnt[i];
        offs[i] = run;
        cnt[i] = run;      // cursor for scatter
        run += cv;
    }
    if (t == 0) offs[NN] = NE;
}

// K2c: per-edge logits + CSR scatter of (src, ex). 4 lanes per edge.
__launch_bounds__(256)
__global__ void k_edge2(const float* __restrict__ edge_h, const int* __restrict__ src,
                        const int* __restrict__ dst, float* __restrict__ ws) {
    const float* p = ws + OFF_P;
    int* run = (int*)(ws + OFF_CNT);
    float2* pay = reinterpret_cast<float2*>(ws + OFF_PAY);
    const float cterm = ws[OFF_C];
    const int part = threadIdx.x & 3;

    float4 pf[6];
    #pragma unroll
    for (int j = 0; j < 6; ++j)
        pf[j] = *reinterpret_cast<const float4*>(p + part * 4 + j * 16);
    const float ptail = p[96 + part];

    const int groups_per_iter = (gridDim.x * blockDim.x) >> 2;
    const int g0 = (blockIdx.x * blockDim.x + threadIdx.x) >> 2;

    for (int e = g0; e < NE; e += groups_per_iter) {
        const float* eh = edge_h + (size_t)e * DD;
        float pd = 0.f;
        #pragma unroll
        for (int j = 0; j < 6; ++j) {
            float4 v = *reinterpret_cast<const float4*>(eh + part * 4 + j * 16);
            pd = fmaf(v.x, pf[j].x, pd);
            pd = fmaf(v.y, pf[j].y, pd);
            pd = fmaf(v.z, pf[j].z, pd);
            pd = fmaf(v.w, pf[j].w, pd);
        }
        pd = fmaf(eh[96 + part], ptail, pd);
        pd += __shfl_xor(pd, 1);
        pd += __shfl_xor(pd, 2);

        if (part == 0) {
            int sn = src[e], dn = dst[e];
            float a = pd + ws[OFF_S + sn] + ws[OFF_T + dn] + cterm;
            float ev = a > 0.f ? a : 0.01f * a;
            float ex = __expf(ev);
            int pos = atomicAdd(&run[dn], 1);
            float2 pl; pl.x = __int_as_float(sn); pl.y = ex;
            pay[pos] = pl;
        }
    }
}

// K3: per-node gather. 25 threads per node, one float4 column-chunk each.
__launch_bounds__(256)
__global__ void k_gather(float* __restrict__ h, const float* __restrict__ ws) {
    int i = blockIdx.x * blockDim.x + threadIdx.x;
    if (i >= NN * 25) return;
    int n = i / 25;
    int c = i - n * 25;
    const int* offs = (const int*)(ws + OFF_OFFS);
    const float2* pay = reinterpret_cast<const float2*>(ws + OFF_PAY);
    const float* z = ws + OFF_Z;

    int beg = offs[n], end = offs[n + 1];
    float4 acc = make_float4(0.f, 0.f, 0.f, 0.f);
    float den = 0.f;
    for (int e = beg; e < end; ++e) {
        float2 pl = pay[e];
        int sn = __float_as_int(pl.x);
        float ex = pl.y;
        den += ex;
        float4 v = *reinterpret_cast<const float4*>(z + (size_t)sn * DD + c * 4);
        acc.x = fmaf(ex, v.x, acc.x);
        acc.y = fmaf(ex, v.y, acc.y);
        acc.z = fmaf(ex, v.z, acc.z);
        acc.w = fmaf(ex, v.w, acc.w);
    }
    float inv = (den > 0.f) ? 1.0f / den : 0.f;
    acc.x *= inv; acc.y *= inv; acc.z *= inv; acc.w *= inv;
    *reinterpret_cast<float4*>(h + (size_t)n * DD + c * 4) = acc;
}

extern "C" void kernel_launch(void* const* d_in, const int* in_sizes, int n_in,
                              void* d_out, int out_size, void* d_ws, size_t ws_size,
                              hipStream_t stream) {
    const float* x      = (const float*)d_in[0];
    const float* edge_h = (const float*)d_in[1];
    const int*   src    = (const int*)d_in[2];
    const int*   dst    = (const int*)d_in[3];
    const float* W_fc   = (const float*)d_in[4];
    const float* W_rel  = (const float*)d_in[5];
    const float* b_rel  = (const float*)d_in[6];
    const float* W_attn = (const float*)d_in[7];
    float* h  = (float*)d_out;
    float* ws = (float*)d_ws;

    hipMemsetAsync(ws + OFF_CNT, 0, (size_t)NN * sizeof(int), stream);

    k_prep<<<1, 128, 0, stream>>>(W_rel, b_rel, W_attn, ws);
    k_fc<<<(NN + 127) / 128, 128, 0, stream>>>(x, W_fc, W_attn, ws);
    k_hist<<<(NE + 255) / 256, 256, 0, stream>>>(dst, ws);
    k_scan<<<1, SCAN_T, 0, stream>>>(ws);
    k_edge2<<<2048, 256, 0, stream>>>(edge_h, src, dst, ws);
    k_gather<<<(NN * 25 + 255) / 256, 256, 0, stream>>>(h, ws);
}

// Round 3
// 180.747 us; speedup vs baseline: 5.6666x; 1.5364x over previous
//
#include <hip/hip_runtime.h>
#include <hip/hip_bf16.h>

#define NN 50000
#define NE 400000
#define DD 100

// workspace layout (float offsets)
#define OFF_P    0
#define OFF_Q    112
#define OFF_C    224
#define OFF_S    240
#define OFF_T    (OFF_S + NN)          // 50240
#define OFF_CNT  (OFF_T + NN)          // 100240  (ints; becomes run-cursor after scan)
#define OFF_OFFS (OFF_CNT + NN)        // 150240  (ints, NN+1)
#define OFF_AUX  (OFF_OFFS + NN + 16)  // 200256  (ints, 64)
#define OFF_PAY  (OFF_AUX + 64)        // 200320  (float2 per edge: src bits, ex)
#define OFF_Z    (OFF_PAY + 2 * NE)    // 1000320

#define NSCB ((NN + 1023) / 1024)      // 49 scan blocks

// K0: fold W_rel/b_rel/W_attn into p[100], q[100], c
__global__ void k_prep(const float* __restrict__ W_rel, const float* __restrict__ b_rel,
                       const float* __restrict__ W_attn, float* __restrict__ ws) {
    int t = threadIdx.x;
    if (t < DD) {
        float accp = 0.f, accq = 0.f;
        for (int j = 0; j < DD; ++j) {
            float v = W_attn[DD + j];
            accp = fmaf(W_rel[t * DD + j], v, accp);
            accq = fmaf(W_rel[(DD + t) * DD + j], v, accq);
        }
        ws[OFF_P + t] = accp;
        ws[OFF_Q + t] = accq;
    } else if (t == DD) {
        float accc = 0.f;
        for (int j = 0; j < DD; ++j) accc = fmaf(b_rel[j], W_attn[DD + j], accc);
        ws[OFF_C] = accc;
    }
}

// K1: z = x @ W_fc (thread = row, x tile in LDS), plus s[i]=z_i.u, t[i]=z_i.q
__launch_bounds__(128)
__global__ void k_fc(const float* __restrict__ x, const float* __restrict__ W_fc,
                     const float* __restrict__ W_attn, float* __restrict__ ws) {
    __shared__ float xs[128 * 101];
    int tid = threadIdx.x;
    int row0 = blockIdx.x * 128;
    int nrows = NN - row0; if (nrows > 128) nrows = 128;
    int n4 = nrows * 25;
    const float4* x4 = reinterpret_cast<const float4*>(x + (size_t)row0 * DD);
    for (int i = tid; i < 128 * 25; i += 128) {
        float4 v = (i < n4) ? x4[i] : make_float4(0.f, 0.f, 0.f, 0.f);
        int r = i / 25, c4 = i - r * 25;
        int base = r * 101 + c4 * 4;
        xs[base] = v.x; xs[base + 1] = v.y; xs[base + 2] = v.z; xs[base + 3] = v.w;
    }
    __syncthreads();

    int row = row0 + tid;
    float z_s = 0.f, z_t = 0.f;
    float* zrow = ws + OFF_Z + (size_t)row * DD;
    for (int half = 0; half < 2; ++half) {
        float acc[50];
        #pragma unroll
        for (int c = 0; c < 50; ++c) acc[c] = 0.f;
        const float* Wb = W_fc + half * 50;           // uniform -> s_load
        for (int k = 0; k < DD; ++k) {
            float xv = xs[tid * 101 + k];
            #pragma unroll
            for (int c = 0; c < 50; ++c) acc[c] = fmaf(xv, Wb[k * DD + c], acc[c]);
        }
        if (row < NN) {
            const float* u = W_attn + half * 50;
            const float* q = ws + OFF_Q + half * 50;
            #pragma unroll
            for (int c = 0; c < 50; ++c) {
                z_s = fmaf(acc[c], u[c], z_s);
                z_t = fmaf(acc[c], q[c], z_t);
            }
            #pragma unroll
            for (int c = 0; c < 50; c += 2) {
                float2 st; st.x = acc[c]; st.y = acc[c + 1];
                *reinterpret_cast<float2*>(zrow + half * 50 + c) = st;
            }
        }
    }
    if (row < NN) { ws[OFF_S + row] = z_s; ws[OFF_T + row] = z_t; }
}

// K2a: histogram of dst
__global__ void k_hist(const int* __restrict__ dst, float* __restrict__ ws) {
    int e = blockIdx.x * blockDim.x + threadIdx.x;
    if (e < NE) {
        int* cnt = (int*)(ws + OFF_CNT);
        atomicAdd(&cnt[dst[e]], 1);
    }
}

// K2b-1: per-block exclusive scan (1024 nodes/block, 4/thread), totals -> aux
__launch_bounds__(256)
__global__ void k_scan1(float* __restrict__ ws) {
    __shared__ int sums[256];
    int* cnt  = (int*)(ws + OFF_CNT);
    int* offs = (int*)(ws + OFF_OFFS);
    int* aux  = (int*)(ws + OFF_AUX);
    int t = threadIdx.x, b = blockIdx.x;
    int base = b * 1024 + t * 4;
    int v0 = 0, v1 = 0, v2 = 0, v3 = 0;
    if (base + 3 < NN) {
        int4 c = *reinterpret_cast<const int4*>(cnt + base);
        v0 = c.x; v1 = c.y; v2 = c.z; v3 = c.w;
    } else {
        if (base + 0 < NN) v0 = cnt[base + 0];
        if (base + 1 < NN) v1 = cnt[base + 1];
        if (base + 2 < NN) v2 = cnt[base + 2];
    }
    int s = v0 + v1 + v2 + v3;
    sums[t] = s;
    for (int off = 1; off < 256; off <<= 1) {
        __syncthreads();
        int v = (t >= off) ? sums[t - off] : 0;
        __syncthreads();
        sums[t] += v;
    }
    __syncthreads();
    int tb = sums[t] - s;  // exclusive base within block
    int e0 = tb, e1 = tb + v0, e2 = e1 + v1, e3 = e2 + v2;
    if (base + 3 < NN) {
        int4 o; o.x = e0; o.y = e1; o.z = e2; o.w = e3;
        *reinterpret_cast<int4*>(offs + base) = o;
    } else {
        if (base + 0 < NN) offs[base + 0] = e0;
        if (base + 1 < NN) offs[base + 1] = e1;
        if (base + 2 < NN) offs[base + 2] = e2;
    }
    if (t == 255) aux[b] = sums[255];
}

// K2b-2: scan the 49 block totals (one wave, in-register)
__global__ void k_scan2(float* __restrict__ ws) {
    int* aux = (int*)(ws + OFF_AUX);
    int t = threadIdx.x;                 // 64 threads
    int v = (t < NSCB) ? aux[t] : 0;
    int inc = v;
    #pragma unroll
    for (int d = 1; d < 64; d <<= 1) {
        int n = __shfl_up(inc, d);
        if (t >= d) inc += n;
    }
    if (t < NSCB) aux[t] = inc - v;      // exclusive block base
}

// K2b-3: add block base; offs final, cnt := cursor copy
__launch_bounds__(256)
__global__ void k_scan3(float* __restrict__ ws) {
    int* cnt  = (int*)(ws + OFF_CNT);
    int* offs = (int*)(ws + OFF_OFFS);
    const int* aux = (const int*)(ws + OFF_AUX);
    int t = threadIdx.x, b = blockIdx.x;
    int add = aux[b];
    int base = b * 1024 + t * 4;
    if (base + 3 < NN) {
        int4 o = *reinterpret_cast<int4*>(offs + base);
        o.x += add; o.y += add; o.z += add; o.w += add;
        *reinterpret_cast<int4*>(offs + base) = o;
        *reinterpret_cast<int4*>(cnt + base) = o;
    } else {
        for (int k = 0; k < 4; ++k)
            if (base + k < NN) { int v = offs[base + k] + add; offs[base + k] = v; cnt[base + k] = v; }
    }
    if (b == 0 && t == 0) offs[NN] = NE;
}

// K2c: per-edge logits + CSR scatter of (src, ex). 4 lanes per edge.
__launch_bounds__(256)
__global__ void k_edge2(const float* __restrict__ edge_h, const int* __restrict__ src,
                        const int* __restrict__ dst, float* __restrict__ ws) {
    const float* p = ws + OFF_P;
    int* run = (int*)(ws + OFF_CNT);
    float2* pay = reinterpret_cast<float2*>(ws + OFF_PAY);
    const float cterm = ws[OFF_C];
    const int part = threadIdx.x & 3;

    float4 pf[6];
    #pragma unroll
    for (int j = 0; j < 6; ++j)
        pf[j] = *reinterpret_cast<const float4*>(p + part * 4 + j * 16);
    const float ptail = p[96 + part];

    const int groups_per_iter = (gridDim.x * blockDim.x) >> 2;
    const int g0 = (blockIdx.x * blockDim.x + threadIdx.x) >> 2;

    for (int e = g0; e < NE; e += groups_per_iter) {
        const float* eh = edge_h + (size_t)e * DD;
        float pd = 0.f;
        #pragma unroll
        for (int j = 0; j < 6; ++j) {
            float4 v = *reinterpret_cast<const float4*>(eh + part * 4 + j * 16);
            pd = fmaf(v.x, pf[j].x, pd);
            pd = fmaf(v.y, pf[j].y, pd);
            pd = fmaf(v.z, pf[j].z, pd);
            pd = fmaf(v.w, pf[j].w, pd);
        }
        pd = fmaf(eh[96 + part], ptail, pd);
        pd += __shfl_xor(pd, 1);
        pd += __shfl_xor(pd, 2);

        if (part == 0) {
            int sn = src[e], dn = dst[e];
            float a = pd + ws[OFF_S + sn] + ws[OFF_T + dn] + cterm;
            float ev = a > 0.f ? a : 0.01f * a;
            float ex = __expf(ev);
            int pos = atomicAdd(&run[dn], 1);
            float2 pl; pl.x = __int_as_float(sn); pl.y = ex;
            pay[pos] = pl;
        }
    }
}

// K3: per-node gather. 25 threads per node, one float4 column-chunk each.
__launch_bounds__(256)
__global__ void k_gather(float* __restrict__ h, const float* __restrict__ ws) {
    int i = blockIdx.x * blockDim.x + threadIdx.x;
    if (i >= NN * 25) return;
    int n = i / 25;
    int c = i - n * 25;
    const int* offs = (const int*)(ws + OFF_OFFS);
    const float2* pay = reinterpret_cast<const float2*>(ws + OFF_PAY);
    const float* z = ws + OFF_Z;

    int beg = offs[n], end = offs[n + 1];
    float4 acc = make_float4(0.f, 0.f, 0.f, 0.f);
    float den = 0.f;
    for (int e = beg; e < end; ++e) {
        float2 pl = pay[e];
        int sn = __float_as_int(pl.x);
        float ex = pl.y;
        den += ex;
        float4 v = *reinterpret_cast<const float4*>(z + (size_t)sn * DD + c * 4);
        acc.x = fmaf(ex, v.x, acc.x);
        acc.y = fmaf(ex, v.y, acc.y);
        acc.z = fmaf(ex, v.z, acc.z);
        acc.w = fmaf(ex, v.w, acc.w);
    }
    float inv = (den > 0.f) ? 1.0f / den : 0.f;
    acc.x *= inv; acc.y *= inv; acc.z *= inv; acc.w *= inv;
    *reinterpret_cast<float4*>(h + (size_t)n * DD + c * 4) = acc;
}

extern "C" void kernel_launch(void* const* d_in, const int* in_sizes, int n_in,
                              void* d_out, int out_size, void* d_ws, size_t ws_size,
                              hipStream_t stream) {
    const float* x      = (const float*)d_in[0];
    const float* edge_h = (const float*)d_in[1];
    const int*   src    = (const int*)d_in[2];
    const int*   dst    = (const int*)d_in[3];
    const float* W_fc   = (const float*)d_in[4];
    const float* W_rel  = (const float*)d_in[5];
    const float* b_rel  = (const float*)d_in[6];
    const float* W_attn = (const float*)d_in[7];
    float* h  = (float*)d_out;
    float* ws = (float*)d_ws;

    hipMemsetAsync(ws + OFF_CNT, 0, (size_t)NN * sizeof(int), stream);

    k_prep<<<1, 128, 0, stream>>>(W_rel, b_rel, W_attn, ws);
    k_fc<<<(NN + 127) / 128, 128, 0, stream>>>(x, W_fc, W_attn, ws);
    k_hist<<<(NE + 255) / 256, 256, 0, stream>>>(dst, ws);
    k_scan1<<<NSCB, 256, 0, stream>>>(ws);
    k_scan2<<<1, 64, 0, stream>>>(ws);
    k_scan3<<<NSCB, 256, 0, stream>>>(ws);
    k_edge2<<<2048, 256, 0, stream>>>(edge_h, src, dst, ws);
    k_gather<<<(NN * 25 + 255) / 256, 256, 0, stream>>>(h, ws);
}

// Round 4
// 135.630 us; speedup vs baseline: 7.5515x; 1.3326x over previous
//
#include <hip/hip_runtime.h>
#include <hip/hip_bf16.h>

#define NN 50000
#define NE 400000
#define DD 100

// workspace layout (float offsets)
#define OFF_P    0
#define OFF_Q    112
#define OFF_C    224
#define OFF_S    240
#define OFF_T    (OFF_S + NN)          // 50240
#define OFF_CNT  (OFF_T + NN)          // 100240  (ints; becomes run-cursor after scan)
#define OFF_OFFS (OFF_CNT + NN)        // 150240  (ints, NN+1)
#define OFF_AUX  (OFF_OFFS + NN + 16)  // 200256  (ints, 64)
#define OFF_PAY  (OFF_AUX + 64)        // 200320  (float2 per edge: src bits, ex)
#define OFF_Z    (OFF_PAY + 2 * NE)    // 1000320

#define NSCB ((NN + 1023) / 1024)      // 49 scan blocks
#define FC_ROWS 64

// K0: fold W_rel/b_rel/W_attn into p[100], q[100], c
__global__ void k_prep(const float* __restrict__ W_rel, const float* __restrict__ b_rel,
                       const float* __restrict__ W_attn, float* __restrict__ ws) {
    int t = threadIdx.x;
    if (t < DD) {
        float accp = 0.f, accq = 0.f;
        for (int j = 0; j < DD; ++j) {
            float v = W_attn[DD + j];
            accp = fmaf(W_rel[t * DD + j], v, accp);
            accq = fmaf(W_rel[(DD + t) * DD + j], v, accq);
        }
        ws[OFF_P + t] = accp;
        ws[OFF_Q + t] = accq;
    } else if (t == DD) {
        float accc = 0.f;
        for (int j = 0; j < DD; ++j) accc = fmaf(b_rel[j], W_attn[DD + j], accc);
        ws[OFF_C] = accc;
    }
}

// K1: z = x @ W_fc. 256 thr = 4 waves; wave p owns 25-col slice (W address
// wave-uniform -> s_load broadcast); thread = one of 64 rows. x tile in LDS,
// reused in-place as z tile for coalesced output. s,t reduced across waves.
__launch_bounds__(256)
__global__ void k_fc(const float* __restrict__ x, const float* __restrict__ W_fc,
                     const float* __restrict__ W_attn, float* __restrict__ ws) {
    __shared__ float xs[FC_ROWS * 101];   // pad 101: (5r+k)%32 -> 2-way max (free)
    __shared__ float sred[8][FC_ROWS];
    int tid = threadIdx.x;
    int row0 = blockIdx.x * FC_ROWS;
    int nrows = NN - row0; if (nrows > FC_ROWS) nrows = FC_ROWS;
    int n4 = nrows * 25;

    const float4* x4 = reinterpret_cast<const float4*>(x + (size_t)row0 * DD);
    for (int i = tid; i < FC_ROWS * 25; i += 256) {
        float4 v = (i < n4) ? x4[i] : make_float4(0.f, 0.f, 0.f, 0.f);
        int r = i / 25, c4 = i - r * 25;
        int base = r * 101 + c4 * 4;
        xs[base] = v.x; xs[base + 1] = v.y; xs[base + 2] = v.z; xs[base + 3] = v.w;
    }
    __syncthreads();

    const int p = __builtin_amdgcn_readfirstlane(tid >> 6);  // wave id, SGPR
    const int r = tid & 63;
    const float* Wp = W_fc + p * 25;      // wave-uniform -> scalar loads

    float acc[25];
    #pragma unroll
    for (int j = 0; j < 25; ++j) acc[j] = 0.f;
    for (int k = 0; k < DD; ++k) {
        float xv = xs[r * 101 + k];
        #pragma unroll
        for (int j = 0; j < 25; ++j) acc[j] = fmaf(xv, Wp[k * DD + j], acc[j]);
    }

    // s,t partials over this wave's 25 columns
    const float* u = W_attn + p * 25;     // wave-uniform
    const float* q = ws + OFF_Q + p * 25; // wave-uniform
    float zs_ = 0.f, zt_ = 0.f;
    #pragma unroll
    for (int j = 0; j < 25; ++j) {
        zs_ = fmaf(acc[j], u[j], zs_);
        zt_ = fmaf(acc[j], q[j], zt_);
    }
    sred[p][r] = zs_; sred[4 + p][r] = zt_;
    __syncthreads();                      // all xs reads complete

    // restage z into xs (stride 100, no pad -> float4-aligned flat tile)
    #pragma unroll
    for (int j = 0; j < 25; ++j) xs[r * 100 + p * 25 + j] = acc[j];
    __syncthreads();

    // coalesced float4 store of the z tile
    float* zbase = ws + OFF_Z + (size_t)row0 * DD;
    for (int i = tid; i < n4; i += 256) {
        float4 v = *reinterpret_cast<const float4*>(xs + i * 4);
        *reinterpret_cast<float4*>(zbase + (size_t)i * 4) = v;
    }
    if (tid < nrows) {
        ws[OFF_S + row0 + tid] = sred[0][tid] + sred[1][tid] + sred[2][tid] + sred[3][tid];
        ws[OFF_T + row0 + tid] = sred[4][tid] + sred[5][tid] + sred[6][tid] + sred[7][tid];
    }
}

// K2a: histogram of dst
__global__ void k_hist(const int* __restrict__ dst, float* __restrict__ ws) {
    int e = blockIdx.x * blockDim.x + threadIdx.x;
    if (e < NE) {
        int* cnt = (int*)(ws + OFF_CNT);
        atomicAdd(&cnt[dst[e]], 1);
    }
}

// K2b-1: per-block exclusive scan (1024 nodes/block, 4/thread), totals -> aux
__launch_bounds__(256)
__global__ void k_scan1(float* __restrict__ ws) {
    __shared__ int sums[256];
    int* cnt  = (int*)(ws + OFF_CNT);
    int* offs = (int*)(ws + OFF_OFFS);
    int* aux  = (int*)(ws + OFF_AUX);
    int t = threadIdx.x, b = blockIdx.x;
    int base = b * 1024 + t * 4;
    int v0 = 0, v1 = 0, v2 = 0, v3 = 0;
    if (base + 3 < NN) {
        int4 c = *reinterpret_cast<const int4*>(cnt + base);
        v0 = c.x; v1 = c.y; v2 = c.z; v3 = c.w;
    } else {
        if (base + 0 < NN) v0 = cnt[base + 0];
        if (base + 1 < NN) v1 = cnt[base + 1];
        if (base + 2 < NN) v2 = cnt[base + 2];
    }
    int s = v0 + v1 + v2 + v3;
    sums[t] = s;
    for (int off = 1; off < 256; off <<= 1) {
        __syncthreads();
        int v = (t >= off) ? sums[t - off] : 0;
        __syncthreads();
        sums[t] += v;
    }
    __syncthreads();
    int tb = sums[t] - s;
    int e0 = tb, e1 = tb + v0, e2 = e1 + v1, e3 = e2 + v2;
    if (base + 3 < NN) {
        int4 o; o.x = e0; o.y = e1; o.z = e2; o.w = e3;
        *reinterpret_cast<int4*>(offs + base) = o;
    } else {
        if (base + 0 < NN) offs[base + 0] = e0;
        if (base + 1 < NN) offs[base + 1] = e1;
        if (base + 2 < NN) offs[base + 2] = e2;
    }
    if (t == 255) aux[b] = sums[255];
}

// K2b-2: scan the 49 block totals (one wave, in-register)
__global__ void k_scan2(float* __restrict__ ws) {
    int* aux = (int*)(ws + OFF_AUX);
    int t = threadIdx.x;
    int v = (t < NSCB) ? aux[t] : 0;
    int inc = v;
    #pragma unroll
    for (int d = 1; d < 64; d <<= 1) {
        int n = __shfl_up(inc, d);
        if (t >= d) inc += n;
    }
    if (t < NSCB) aux[t] = inc - v;
}

// K2b-3: add block base; offs final, cnt := cursor copy
__launch_bounds__(256)
__global__ void k_scan3(float* __restrict__ ws) {
    int* cnt  = (int*)(ws + OFF_CNT);
    int* offs = (int*)(ws + OFF_OFFS);
    const int* aux = (const int*)(ws + OFF_AUX);
    int t = threadIdx.x, b = blockIdx.x;
    int add = aux[b];
    int base = b * 1024 + t * 4;
    if (base + 3 < NN) {
        int4 o = *reinterpret_cast<int4*>(offs + base);
        o.x += add; o.y += add; o.z += add; o.w += add;
        *reinterpret_cast<int4*>(offs + base) = o;
        *reinterpret_cast<int4*>(cnt + base) = o;
    } else {
        for (int k = 0; k < 4; ++k)
            if (base + k < NN) { int v = offs[base + k] + add; offs[base + k] = v; cnt[base + k] = v; }
    }
    if (b == 0 && t == 0) offs[NN] = NE;
}

// K2c: per-edge logits + CSR scatter of (src, ex). 4 lanes per edge.
__launch_bounds__(256)
__global__ void k_edge2(const float* __restrict__ edge_h, const int* __restrict__ src,
                        const int* __restrict__ dst, float* __restrict__ ws) {
    const float* p = ws + OFF_P;
    int* run = (int*)(ws + OFF_CNT);
    float2* pay = reinterpret_cast<float2*>(ws + OFF_PAY);
    const float cterm = ws[OFF_C];
    const int part = threadIdx.x & 3;

    float4 pf[6];
    #pragma unroll
    for (int j = 0; j < 6; ++j)
        pf[j] = *reinterpret_cast<const float4*>(p + part * 4 + j * 16);
    const float ptail = p[96 + part];

    const int groups_per_iter = (gridDim.x * blockDim.x) >> 2;
    const int g0 = (blockIdx.x * blockDim.x + threadIdx.x) >> 2;

    for (int e = g0; e < NE; e += groups_per_iter) {
        const float* eh = edge_h + (size_t)e * DD;
        float pd = 0.f;
        #pragma unroll
        for (int j = 0; j < 6; ++j) {
            float4 v = *reinterpret_cast<const float4*>(eh + part * 4 + j * 16);
            pd = fmaf(v.x, pf[j].x, pd);
            pd = fmaf(v.y, pf[j].y, pd);
            pd = fmaf(v.z, pf[j].z, pd);
            pd = fmaf(v.w, pf[j].w, pd);
        }
        pd = fmaf(eh[96 + part], ptail, pd);
        pd += __shfl_xor(pd, 1);
        pd += __shfl_xor(pd, 2);

        if (part == 0) {
            int sn = src[e], dn = dst[e];
            float a = pd + ws[OFF_S + sn] + ws[OFF_T + dn] + cterm;
            float ev = a > 0.f ? a : 0.01f * a;
            float ex = __expf(ev);
            int pos = atomicAdd(&run[dn], 1);
            float2 pl; pl.x = __int_as_float(sn); pl.y = ex;
            pay[pos] = pl;
        }
    }
}

// K3: per-node gather. 25 threads per node, one float4 column-chunk each.
__launch_bounds__(256)
__global__ void k_gather(float* __restrict__ h, const float* __restrict__ ws) {
    int i = blockIdx.x * blockDim.x + threadIdx.x;
    if (i >= NN * 25) return;
    int n = i / 25;
    int c = i - n * 25;
    const int* offs = (const int*)(ws + OFF_OFFS);
    const float2* pay = reinterpret_cast<const float2*>(ws + OFF_PAY);
    const float* z = ws + OFF_Z;

    int beg = offs[n], end = offs[n + 1];
    float4 acc = make_float4(0.f, 0.f, 0.f, 0.f);
    float den = 0.f;
    for (int e = beg; e < end; ++e) {
        float2 pl = pay[e];
        int sn = __float_as_int(pl.x);
        float ex = pl.y;
        den += ex;
        float4 v = *reinterpret_cast<const float4*>(z + (size_t)sn * DD + c * 4);
        acc.x = fmaf(ex, v.x, acc.x);
        acc.y = fmaf(ex, v.y, acc.y);
        acc.z = fmaf(ex, v.z, acc.z);
        acc.w = fmaf(ex, v.w, acc.w);
    }
    float inv = (den > 0.f) ? 1.0f / den : 0.f;
    acc.x *= inv; acc.y *= inv; acc.z *= inv; acc.w *= inv;
    *reinterpret_cast<float4*>(h + (size_t)n * DD + c * 4) = acc;
}

extern "C" void kernel_launch(void* const* d_in, const int* in_sizes, int n_in,
                              void* d_out, int out_size, void* d_ws, size_t ws_size,
                              hipStream_t stream) {
    const float* x      = (const float*)d_in[0];
    const float* edge_h = (const float*)d_in[1];
    const int*   src    = (const int*)d_in[2];
    const int*   dst    = (const int*)d_in[3];
    const float* W_fc   = (const float*)d_in[4];
    const float* W_rel  = (const float*)d_in[5];
    const float* b_rel  = (const float*)d_in[6];
    const float* W_attn = (const float*)d_in[7];
    float* h  = (float*)d_out;
    float* ws = (float*)d_ws;

    hipMemsetAsync(ws + OFF_CNT, 0, (size_t)NN * sizeof(int), stream);

    k_prep<<<1, 128, 0, stream>>>(W_rel, b_rel, W_attn, ws);
    k_fc<<<(NN + FC_ROWS - 1) / FC_ROWS, 256, 0, stream>>>(x, W_fc, W_attn, ws);
    k_hist<<<(NE + 255) / 256, 256, 0, stream>>>(dst, ws);
    k_scan1<<<NSCB, 256, 0, stream>>>(ws);
    k_scan2<<<1, 64, 0, stream>>>(ws);
    k_scan3<<<NSCB, 256, 0, stream>>>(ws);
    k_edge2<<<2048, 256, 0, stream>>>(edge_h, src, dst, ws);
    k_gather<<<(NN * 25 + 255) / 256, 256, 0, stream>>>(h, ws);
}

// Round 5
// 122.006 us; speedup vs baseline: 8.3948x; 1.1117x over previous
//
#include <hip/hip_runtime.h>
#include <hip/hip_bf16.h>

#define NN 50000
#define NE 400000
#define DD 100

// workspace layout (float offsets)
#define OFF_P    0
#define OFF_Q    112
#define OFF_C    224
#define OFF_S    240
#define OFF_T    (OFF_S + NN)          // 50240
#define OFF_CNT  (OFF_T + NN)          // 100240  (ints; becomes run-cursor after scan)
#define OFF_OFFS (OFF_CNT + NN)        // 150240  (ints, NN+1)
#define OFF_AUX  (OFF_OFFS + NN + 16)  // 200256  (ints, 64)
#define OFF_PAY  (OFF_AUX + 64)        // 200320  (float2 per edge: src bits, ex)
#define OFF_Z    (OFF_PAY + 2 * NE)    // 1000320

#define NSCB ((NN + 1023) / 1024)      // 49 scan blocks
#define FC_ROWS 64
#define NFCB ((NN + FC_ROWS - 1) / FC_ROWS)   // 782 fc blocks
#define NHB  391                               // hist blocks (x256 thr = 100096)

// K0: block 0 folds W_rel/b_rel/W_attn into p[100], q[100], c.
//     blocks 1..49 zero cnt[] (replaces the pathologically slow fill kernel).
__global__ void k_prep(const float* __restrict__ W_rel, const float* __restrict__ b_rel,
                       const float* __restrict__ W_attn, float* __restrict__ ws) {
    int b = blockIdx.x;
    if (b == 0) {
        int t = threadIdx.x;
        if (t < DD) {
            float accp = 0.f, accq = 0.f;
            for (int j = 0; j < DD; ++j) {
                float v = W_attn[DD + j];
                accp = fmaf(W_rel[t * DD + j], v, accp);
                accq = fmaf(W_rel[(DD + t) * DD + j], v, accq);
            }
            ws[OFF_P + t] = accp;
            ws[OFF_Q + t] = accq;
        } else if (t == DD) {
            float accc = 0.f;
            for (int j = 0; j < DD; ++j) accc = fmaf(b_rel[j], W_attn[DD + j], accc);
            ws[OFF_C] = accc;
        }
    } else {
        int* cnt = (int*)(ws + OFF_CNT);
        int i0 = (b - 1) * 1024 + threadIdx.x;
        int lim = (b - 1) * 1024 + 1024; if (lim > NN) lim = NN;
        for (int i = i0; i < lim; i += 256) cnt[i] = 0;
    }
}

// K1 (role-split): blocks [0,NFCB): z = x @ W_fc + s,t  (wave = 25-col slice,
// thread = row; W address wave-uniform -> s_load). blocks [NFCB,NFCB+NHB):
// histogram of dst into cnt (cnt zeroed by k_prep).
__launch_bounds__(256)
__global__ void k_fc(const float* __restrict__ x, const float* __restrict__ W_fc,
                     const float* __restrict__ W_attn, const int* __restrict__ dst,
                     float* __restrict__ ws) {
    __shared__ float xs[FC_ROWS * 101];
    __shared__ float sred[8][FC_ROWS];
    int tid = threadIdx.x;

    if (blockIdx.x >= NFCB) {
        // histogram role
        int* cnt = (int*)(ws + OFF_CNT);
        int e = (blockIdx.x - NFCB) * 256 + tid;
        for (; e < NE; e += NHB * 256) atomicAdd(&cnt[dst[e]], 1);
        return;
    }

    int row0 = blockIdx.x * FC_ROWS;
    int nrows = NN - row0; if (nrows > FC_ROWS) nrows = FC_ROWS;
    int n4 = nrows * 25;

    const float4* x4 = reinterpret_cast<const float4*>(x + (size_t)row0 * DD);
    for (int i = tid; i < FC_ROWS * 25; i += 256) {
        float4 v = (i < n4) ? x4[i] : make_float4(0.f, 0.f, 0.f, 0.f);
        int r = i / 25, c4 = i - r * 25;
        int base = r * 101 + c4 * 4;
        xs[base] = v.x; xs[base + 1] = v.y; xs[base + 2] = v.z; xs[base + 3] = v.w;
    }
    __syncthreads();

    const int p = __builtin_amdgcn_readfirstlane(tid >> 6);
    const int r = tid & 63;
    const float* Wp = W_fc + p * 25;      // wave-uniform -> scalar loads

    float acc[25];
    #pragma unroll
    for (int j = 0; j < 25; ++j) acc[j] = 0.f;
    for (int k = 0; k < DD; ++k) {
        float xv = xs[r * 101 + k];
        #pragma unroll
        for (int j = 0; j < 25; ++j) acc[j] = fmaf(xv, Wp[k * DD + j], acc[j]);
    }

    const float* u = W_attn + p * 25;
    const float* q = ws + OFF_Q + p * 25;
    float zs_ = 0.f, zt_ = 0.f;
    #pragma unroll
    for (int j = 0; j < 25; ++j) {
        zs_ = fmaf(acc[j], u[j], zs_);
        zt_ = fmaf(acc[j], q[j], zt_);
    }
    sred[p][r] = zs_; sred[4 + p][r] = zt_;
    __syncthreads();

    #pragma unroll
    for (int j = 0; j < 25; ++j) xs[r * 100 + p * 25 + j] = acc[j];
    __syncthreads();

    float* zbase = ws + OFF_Z + (size_t)row0 * DD;
    for (int i = tid; i < n4; i += 256) {
        float4 v = *reinterpret_cast<const float4*>(xs + i * 4);
        *reinterpret_cast<float4*>(zbase + (size_t)i * 4) = v;
    }
    if (tid < nrows) {
        ws[OFF_S + row0 + tid] = sred[0][tid] + sred[1][tid] + sred[2][tid] + sred[3][tid];
        ws[OFF_T + row0 + tid] = sred[4][tid] + sred[5][tid] + sred[6][tid] + sred[7][tid];
    }
}

// K2b-1: per-block exclusive scan (1024 nodes/block, 4/thread), totals -> aux
__launch_bounds__(256)
__global__ void k_scan1(float* __restrict__ ws) {
    __shared__ int sums[256];
    int* cnt  = (int*)(ws + OFF_CNT);
    int* offs = (int*)(ws + OFF_OFFS);
    int* aux  = (int*)(ws + OFF_AUX);
    int t = threadIdx.x, b = blockIdx.x;
    int base = b * 1024 + t * 4;
    int v0 = 0, v1 = 0, v2 = 0, v3 = 0;
    if (base + 3 < NN) {
        int4 c = *reinterpret_cast<const int4*>(cnt + base);
        v0 = c.x; v1 = c.y; v2 = c.z; v3 = c.w;
    } else {
        if (base + 0 < NN) v0 = cnt[base + 0];
        if (base + 1 < NN) v1 = cnt[base + 1];
        if (base + 2 < NN) v2 = cnt[base + 2];
    }
    int s = v0 + v1 + v2 + v3;
    sums[t] = s;
    for (int off = 1; off < 256; off <<= 1) {
        __syncthreads();
        int v = (t >= off) ? sums[t - off] : 0;
        __syncthreads();
        sums[t] += v;
    }
    __syncthreads();
    int tb = sums[t] - s;
    int e0 = tb, e1 = tb + v0, e2 = e1 + v1, e3 = e2 + v2;
    if (base + 3 < NN) {
        int4 o; o.x = e0; o.y = e1; o.z = e2; o.w = e3;
        *reinterpret_cast<int4*>(offs + base) = o;
    } else {
        if (base + 0 < NN) offs[base + 0] = e0;
        if (base + 1 < NN) offs[base + 1] = e1;
        if (base + 2 < NN) offs[base + 2] = e2;
    }
    if (t == 255) aux[b] = sums[255];
}

// K2b-2: scan the 49 block totals (one wave, in-register)
__global__ void k_scan2(float* __restrict__ ws) {
    int* aux = (int*)(ws + OFF_AUX);
    int t = threadIdx.x;
    int v = (t < NSCB) ? aux[t] : 0;
    int inc = v;
    #pragma unroll
    for (int d = 1; d < 64; d <<= 1) {
        int n = __shfl_up(inc, d);
        if (t >= d) inc += n;
    }
    if (t < NSCB) aux[t] = inc - v;
}

// K2b-3: add block base; offs final, cnt := cursor copy
__launch_bounds__(256)
__global__ void k_scan3(float* __restrict__ ws) {
    int* cnt  = (int*)(ws + OFF_CNT);
    int* offs = (int*)(ws + OFF_OFFS);
    const int* aux = (const int*)(ws + OFF_AUX);
    int t = threadIdx.x, b = blockIdx.x;
    int add = aux[b];
    int base = b * 1024 + t * 4;
    if (base + 3 < NN) {
        int4 o = *reinterpret_cast<int4*>(offs + base);
        o.x += add; o.y += add; o.z += add; o.w += add;
        *reinterpret_cast<int4*>(offs + base) = o;
        *reinterpret_cast<int4*>(cnt + base) = o;
    } else {
        for (int k = 0; k < 4; ++k)
            if (base + k < NN) { int v = offs[base + k] + add; offs[base + k] = v; cnt[base + k] = v; }
    }
    if (b == 0 && t == 0) offs[NN] = NE;
}

// K2c: per-edge logits + CSR scatter of (src, ex). 4 lanes per edge.
__launch_bounds__(256)
__global__ void k_edge2(const float* __restrict__ edge_h, const int* __restrict__ src,
                        const int* __restrict__ dst, float* __restrict__ ws) {
    const float* p = ws + OFF_P;
    int* run = (int*)(ws + OFF_CNT);
    float2* pay = reinterpret_cast<float2*>(ws + OFF_PAY);
    const float cterm = ws[OFF_C];
    const int part = threadIdx.x & 3;

    float4 pf[6];
    #pragma unroll
    for (int j = 0; j < 6; ++j)
        pf[j] = *reinterpret_cast<const float4*>(p + part * 4 + j * 16);
    const float ptail = p[96 + part];

    const int groups_per_iter = (gridDim.x * blockDim.x) >> 2;
    const int g0 = (blockIdx.x * blockDim.x + threadIdx.x) >> 2;

    for (int e = g0; e < NE; e += groups_per_iter) {
        const float* eh = edge_h + (size_t)e * DD;
        float pd = 0.f;
        #pragma unroll
        for (int j = 0; j < 6; ++j) {
            float4 v = *reinterpret_cast<const float4*>(eh + part * 4 + j * 16);
            pd = fmaf(v.x, pf[j].x, pd);
            pd = fmaf(v.y, pf[j].y, pd);
            pd = fmaf(v.z, pf[j].z, pd);
            pd = fmaf(v.w, pf[j].w, pd);
        }
        pd = fmaf(eh[96 + part], ptail, pd);
        pd += __shfl_xor(pd, 1);
        pd += __shfl_xor(pd, 2);

        if (part == 0) {
            int sn = src[e], dn = dst[e];
            float a = pd + ws[OFF_S + sn] + ws[OFF_T + dn] + cterm;
            float ev = a > 0.f ? a : 0.01f * a;
            float ex = __expf(ev);
            int pos = atomicAdd(&run[dn], 1);
            float2 pl; pl.x = __int_as_float(sn); pl.y = ex;
            pay[pos] = pl;
        }
    }
}

// K3: per-node gather. 25 threads per node, one float4 column-chunk each.
__launch_bounds__(256)
__global__ void k_gather(float* __restrict__ h, const float* __restrict__ ws) {
    int i = blockIdx.x * blockDim.x + threadIdx.x;
    if (i >= NN * 25) return;
    int n = i / 25;
    int c = i - n * 25;
    const int* offs = (const int*)(ws + OFF_OFFS);
    const float2* pay = reinterpret_cast<const float2*>(ws + OFF_PAY);
    const float* z = ws + OFF_Z;

    int beg = offs[n], end = offs[n + 1];
    float4 acc = make_float4(0.f, 0.f, 0.f, 0.f);
    float den = 0.f;
    for (int e = beg; e < end; ++e) {
        float2 pl = pay[e];
        int sn = __float_as_int(pl.x);
        float ex = pl.y;
        den += ex;
        float4 v = *reinterpret_cast<const float4*>(z + (size_t)sn * DD + c * 4);
        acc.x = fmaf(ex, v.x, acc.x);
        acc.y = fmaf(ex, v.y, acc.y);
        acc.z = fmaf(ex, v.z, acc.z);
        acc.w = fmaf(ex, v.w, acc.w);
    }
    float inv = (den > 0.f) ? 1.0f / den : 0.f;
    acc.x *= inv; acc.y *= inv; acc.z *= inv; acc.w *= inv;
    *reinterpret_cast<float4*>(h + (size_t)n * DD + c * 4) = acc;
}

extern "C" void kernel_launch(void* const* d_in, const int* in_sizes, int n_in,
                              void* d_out, int out_size, void* d_ws, size_t ws_size,
                              hipStream_t stream) {
    const float* x      = (const float*)d_in[0];
    const float* edge_h = (const float*)d_in[1];
    const int*   src    = (const int*)d_in[2];
    const int*   dst    = (const int*)d_in[3];
    const float* W_fc   = (const float*)d_in[4];
    const float* W_rel  = (const float*)d_in[5];
    const float* b_rel  = (const float*)d_in[6];
    const float* W_attn = (const float*)d_in[7];
    float* h  = (float*)d_out;
    float* ws = (float*)d_ws;

    k_prep<<<1 + NSCB, 256, 0, stream>>>(W_rel, b_rel, W_attn, ws);
    k_fc<<<NFCB + NHB, 256, 0, stream>>>(x, W_fc, W_attn, dst, ws);
    k_scan1<<<NSCB, 256, 0, stream>>>(ws);
    k_scan2<<<1, 64, 0, stream>>>(ws);
    k_scan3<<<NSCB, 256, 0, stream>>>(ws);
    k_edge2<<<2048, 256, 0, stream>>>(edge_h, src, dst, ws);
    k_gather<<<(NN * 25 + 255) / 256, 256, 0, stream>>>(h, ws);
}